// Round 7
// baseline (242.805 us; speedup 1.0000x reference)
//
#include <hip/hip_runtime.h>

typedef _Float16 half_t;
typedef _Float16 half8 __attribute__((ext_vector_type(8)));
typedef float f32x4 __attribute__((ext_vector_type(4)));

#define NELEM 16384
#define SROW 184   // halves; dword stride 92 = 28 mod 32 -> 2-way (free) on b128 reads

// ---------------------------------------------------------------------------
// Block = 8 elements (160 rows, 10 M-tiles) + 16-row g/joint tile (rows 160-176).
// 4 waves = 2 M-halves (rows 0-80 / 80-160, MT=5) x 2 nt-groups (nt stride 2).
// Single in-place LDS buffer: [sync; load A-frags; sync; MFMA+store] per layer.
// Stale-A is always harmless: B tiles are zero-padded (k>=K, c>=C -> 0) and the
// g/joint tile is zeroed once at start (kills first-launch NaN garbage).
//   B: global pre-swizzled frags [ks][nt][lane][8] (fp16).
//   Layouts (verified): A[m=lane&15][k=quad*8+j], B[k][n=lane&15],
//                       D[row=quad*4+r][col=lane&15].
// ---------------------------------------------------------------------------

template<int KS, int MT>
__device__ __forceinline__ void load_af(half8 (&af)[KS][MT], const half_t* S,
                                        int rbase, int m, int q) {
    #pragma unroll
    for (int ks = 0; ks < KS; ++ks)
        #pragma unroll
        for (int t = 0; t < MT; ++t)
            af[ks][t] = *(const half8*)(S + (rbase + t*16 + m)*SROW + q*8 + ks*32);
}

// EPI: 0 = f16 store at col; 1 = f16 store at 128+col (f park, col<56);
//      2 = logits -> lbuf[rbase+row] (m==0); 3 = gp -> gpb[row*112+col] (row<8).
// INIT==1: add gpb[((rbase+row)/20)*112 + col] (a1 layer).
template<int KS, int MT, int NT, int STRIDE, int EPI, int INIT, bool RELU, bool HASB>
__device__ __forceinline__ void compute(
    const half8 (&af)[KS][MT], half_t* S, int rbase,
    const half_t* __restrict__ wf, const float* __restrict__ bias, int C,
    float* gpb, float* lbuf, float extra, int lane, int nt0)
{
    const int m = lane & 15, q = lane >> 4;
    for (int nt = nt0; nt < NT; nt += STRIDE) {
        const int col = nt*16 + m;
        float bv = 0.f;
        if (HASB) bv = (col < C) ? bias[col] : 0.f;
        f32x4 acc[MT];
        #pragma unroll
        for (int t = 0; t < MT; ++t) acc[t] = f32x4{bv, bv, bv, bv};
        half8 bh[KS];
        #pragma unroll
        for (int ks = 0; ks < KS; ++ks)
            bh[ks] = *(const half8*)(wf + ((size_t)(ks*NT + nt)*64 + lane)*8);
        #pragma unroll
        for (int ks = 0; ks < KS; ++ks)
            #pragma unroll
            for (int t = 0; t < MT; ++t)
                acc[t] = __builtin_amdgcn_mfma_f32_16x16x32_f16(af[ks][t], bh[ks], acc[t], 0,0,0);
        #pragma unroll
        for (int t = 0; t < MT; ++t) {
            #pragma unroll
            for (int r = 0; r < 4; ++r) {
                const int row = t*16 + q*4 + r;
                float v = acc[t][r];
                if (INIT == 1) v += gpb[((rbase + row)/20)*112 + col];
                if (RELU) v = fmaxf(v, 0.f);
                if (EPI == 0) {
                    S[(rbase + row)*SROW + col] = (half_t)v;
                } else if (EPI == 1) {
                    if (col < 56) S[(rbase + row)*SROW + 128 + col] = (half_t)v;
                } else if (EPI == 2) {
                    if (m == 0) lbuf[rbase + row] = v + extra;
                } else if (EPI == 3) {
                    if (row < 8) gpb[row*112 + col] = v;
                }
            }
        }
    }
}

// ---------------------------------------------------------------------------
// Prep: build fp16 weight fragments in ws. One 16x32 tile per block.
// ---------------------------------------------------------------------------
struct PrepDesc { const float* w; half_t* out; int K, C, KS, NT, toff; };
struct PrepArgs { PrepDesc d[11]; };

__global__ __launch_bounds__(64) void k_prep(PrepArgs a) {
    const int blk = blockIdx.x, lane = threadIdx.x;
    int li = 0;
    #pragma unroll
    for (int i = 1; i < 11; ++i) if (blk >= a.d[i].toff) li = i;
    const PrepDesc d = a.d[li];
    const int t = blk - d.toff;
    const int ks = t / d.NT, nt = t - (t / d.NT) * d.NT;
    const int c = nt*16 + (lane & 15);
    half_t* o = d.out + ((size_t)(ks*d.NT + nt))*512 + lane*8;
    #pragma unroll
    for (int j = 0; j < 8; ++j) {
        const int k = ks*32 + (lane >> 4)*8 + j;
        float v = (k < d.K && c < d.C) ? d.w[(size_t)k*d.C + c] : 0.f;
        o[j] = (half_t)v;
    }
}

// ---------------------------------------------------------------------------
// k_main
// ---------------------------------------------------------------------------
__global__ __launch_bounds__(256, 2) void k_main(
    const float* __restrict__ state,
    const half_t* __restrict__ wfrag,
    const float* __restrict__ m1b0, const float* __restrict__ m1b1,
    const float* __restrict__ m2b0, const float* __restrict__ m2b1,
    const float* __restrict__ ab0, const float* __restrict__ ab1,
    const float* __restrict__ ab2,
    const float* __restrict__ m3b0, const float* __restrict__ m3b1,
    const float* __restrict__ m3b2,
    const float* __restrict__ m3w3, const float* __restrict__ m3b3,
    float* __restrict__ out)
{
    __shared__ __align__(16) half_t S[176 * SROW];
    __shared__ float gpb[8 * 112];
    __shared__ float lbuf[160];

    const int tid = threadIdx.x;
    const int wv = tid >> 6, lane = tid & 63;
    const int m = lane & 15, q = lane >> 4;
    const int mh = wv & 1, ng = wv >> 1;
    const int rbase = mh * 80;
    const int ebase = blockIdx.x * 8;

    const half_t* wfL0 = wfrag;
    const half_t* wfL1 = wfL0 + 5120;
    const half_t* wfL2 = wfL1 + 17920;
    const half_t* wfL3 = wfL2 + 14336;
    const half_t* wfL4 = wfL3 + 8192;
    const half_t* wfL5 = wfL4 + 14336;
    const half_t* wfL6 = wfL5 + 14336;
    const half_t* wfL7 = wfL6 + 14336;
    const half_t* wfL8 = wfL7 + 2048;
    const half_t* wfL9 = wfL8 + 10240;
    const half_t* wfL10 = wfL9 + 17920;

    const half8 hz = {0,0,0,0,0,0,0,0};

    // ---- stage: zero x-pad (rows 0-160 cols 0-32) and g/joint tile (rows 160-176)
    for (int u = tid; u < 640; u += 256)
        *(half8*)(S + (u >> 2)*SROW + (u & 3)*8) = hz;
    for (int u = tid; u < 368; u += 256)
        *(half8*)(S + (160 + u/23)*SROW + (u % 23)*8) = hz;
    __syncthreads();
    {   // fill x (coalesced fp32 reads)
        const float* xg = state + (size_t)ebase * 260;
        for (int u = tid; u < 2080; u += 256) {
            const int r = u / 13, c = u - r*13;
            S[r*SROW + c] = (half_t)xg[u];
        }
    }
    __syncthreads();

    // ---- L0: h1 = relu(x @ m1w0 + b)  (in-place, cols 0-160)
    {
        half8 af[1][5]; load_af<1,5>(af, S, rbase, m, q);
        __syncthreads();
        compute<1,5,10,2,0,0,true,true>(af, S, rbase, wfL0, m1b0, 150, gpb, lbuf, 0.f, lane, ng);
    }
    __syncthreads();
    // ---- L1: h = relu(h1 @ m1w1 + b)  (cols 0-112)
    {
        half8 af[5][5]; load_af<5,5>(af, S, rbase, m, q);
        __syncthreads();
        compute<5,5,7,2,0,0,true,true>(af, S, rbase, wfL1, m1b1, 100, gpb, lbuf, 0.f, lane, ng);
    }
    __syncthreads();

    // ---- keep h in regs (serves L2 and L4); g = mean_n h -> rows 160-168
    half8 hf[4][5]; load_af<4,5>(hf, S, rbase, m, q);
    for (int u = tid; u < 800; u += 256) {
        const int e = u / 100, c = u - e*100;
        float s = 0.f;
        #pragma unroll
        for (int n = 0; n < 20; ++n) s += (float)S[(e*20 + n)*SROW + c];
        S[(160 + e)*SROW + c] = (half_t)(s * 0.05f);
    }
    __syncthreads();

    // ---- gp = g @ aw0[100:] -> gpb;  L2: fh = relu(h @ m2w0 + b) (cols 0-112)
    {
        half8 afg[4][1]; load_af<4,1>(afg, S, 160, m, q);
        compute<4,1,7,4,3,0,false,false>(afg, S, 0, wfL5, nullptr, 0, gpb, lbuf, 0.f, lane, wv);
    }
    compute<4,5,7,2,0,0,true,true>(hf, S, rbase, wfL2, m2b0, 100, gpb, lbuf, 0.f, lane, ng);
    __syncthreads();

    // ---- L3: f = fh @ m2w1 + b -> cols 128-184 (disjoint from reads, 1 sync)
    {
        half8 af[4][5]; load_af<4,5>(af, S, rbase, m, q);
        compute<4,5,4,2,1,0,false,true>(af, S, rbase, wfL3, m2b1, 50, gpb, lbuf, 0.f, lane, ng);
    }
    __syncthreads();
    // ---- L4: a1 = relu(h @ aw0[:100] + gp + ab0)  (h from regs, no load)
    compute<4,5,7,2,0,1,true,true>(hf, S, rbase, wfL4, ab0, 100, gpb, lbuf, 0.f, lane, ng);
    __syncthreads();
    // ---- L6: a2 = relu(a1 @ aw1 + ab1)  (in-place)
    {
        half8 af[4][5]; load_af<4,5>(af, S, rbase, m, q);
        __syncthreads();
        compute<4,5,7,2,0,0,true,true>(af, S, rbase, wfL6, ab1, 100, gpb, lbuf, 0.f, lane, ng);
    }
    __syncthreads();
    // ---- L7: logits = a2 @ aw2 + ab2 -> lbuf  (ng==0 waves cover all rows)
    if (ng == 0) {
        half8 af[4][5]; load_af<4,5>(af, S, rbase, m, q);
        compute<4,5,1,2,2,0,false,false>(af, S, rbase, wfL7, nullptr, 0, gpb, lbuf, ab2[0], lane, 0);
    }
    __syncthreads();

    // ---- weighted + self -> joint (rows 160-168, cols 0-56)
    for (int u = tid; u < 448; u += 256) {
        if (u < 400) {
            const int e = u / 50, j = u - e*50;
            float s = 0.f;
            #pragma unroll
            for (int n = 0; n < 20; ++n)
                s += (float)S[(e*20 + n)*SROW + 128 + j] * lbuf[e*20 + n];
            S[(160 + e)*SROW + 6 + j] = (half_t)s;
        } else {
            const int u2 = u - 400, e = u2 / 6, d = u2 - e*6;
            S[(160 + e)*SROW + d] = (half_t)state[(size_t)(ebase + e)*260 + d];
        }
    }
    __syncthreads();

    // ---- head (rows 160-176, MT=1, nt stride 4 across all waves)
    {
        half8 af[2][1]; load_af<2,1>(af, S, 160, m, q);
        __syncthreads();
        compute<2,1,10,4,0,0,true,true>(af, S, 160, wfL8, m3b0, 150, gpb, lbuf, 0.f, lane, wv);
    }
    __syncthreads();
    {
        half8 af[5][1]; load_af<5,1>(af, S, 160, m, q);
        __syncthreads();
        compute<5,1,7,4,0,0,true,true>(af, S, 160, wfL9, m3b1, 100, gpb, lbuf, 0.f, lane, wv);
    }
    __syncthreads();
    {
        half8 af[4][1]; load_af<4,1>(af, S, 160, m, q);
        __syncthreads();
        compute<4,1,7,4,0,0,true,true>(af, S, 160, wfL10, m3b2, 100, gpb, lbuf, 0.f, lane, wv);
    }
    __syncthreads();

    // ---- out[e] = v3[e] . m3w3 + b3  (16 lanes per element, tid<128)
    if (tid < 128) {
        const int e = tid >> 4, k0 = tid & 15;
        float s = 0.f;
        #pragma unroll
        for (int j = 0; j < 7; ++j) {
            const int k = k0 + 16*j;
            if (k < 100) s += (float)S[(160 + e)*SROW + k] * m3w3[k];
        }
        s += __shfl_down(s, 8, 16);
        s += __shfl_down(s, 4, 16);
        s += __shfl_down(s, 2, 16);
        s += __shfl_down(s, 1, 16);
        if (k0 == 0) out[ebase + e] = s + m3b3[0];
    }
}

extern "C" void kernel_launch(void* const* d_in, const int* in_sizes, int n_in,
                              void* d_out, int out_size, void* d_ws, size_t ws_size,
                              hipStream_t stream) {
    const float* state = (const float*)d_in[0];
    const float* m1w0 = (const float*)d_in[1];
    const float* m1b0 = (const float*)d_in[2];
    const float* m1w1 = (const float*)d_in[3];
    const float* m1b1 = (const float*)d_in[4];
    const float* m2w0 = (const float*)d_in[5];
    const float* m2b0 = (const float*)d_in[6];
    const float* m2w1 = (const float*)d_in[7];
    const float* m2b1 = (const float*)d_in[8];
    const float* aw0  = (const float*)d_in[9];
    const float* ab0  = (const float*)d_in[10];
    const float* aw1  = (const float*)d_in[11];
    const float* ab1  = (const float*)d_in[12];
    const float* aw2  = (const float*)d_in[13];
    const float* ab2  = (const float*)d_in[14];
    const float* m3w0 = (const float*)d_in[15];
    const float* m3b0 = (const float*)d_in[16];
    const float* m3w1 = (const float*)d_in[17];
    const float* m3b1 = (const float*)d_in[18];
    const float* m3w2 = (const float*)d_in[19];
    const float* m3b2 = (const float*)d_in[20];
    const float* m3w3 = (const float*)d_in[21];
    const float* m3b3 = (const float*)d_in[22];

    half_t* wfrag = (half_t*)d_ws;   // 266 KB of fragments

    PrepArgs pa;
    int off = 0; size_t hoff = 0; int idx = 0;
    auto add = [&](const float* w, int K, int C, int KS, int NT) {
        pa.d[idx] = PrepDesc{w, wfrag + hoff, K, C, KS, NT, off};
        off += KS*NT;
        hoff += (size_t)KS*NT*512;
        ++idx;
    };
    add(m1w0, 13, 150, 1, 10);          // L0
    add(m1w1, 150, 100, 5, 7);          // L1
    add(m2w0, 100, 100, 4, 7);          // L2
    add(m2w1, 100, 50, 4, 4);           // L3
    add(aw0, 100, 100, 4, 7);           // L4 (rows 0..99)
    add(aw0 + 100*100, 100, 100, 4, 7); // L5 (rows 100..199)
    add(aw1, 100, 100, 4, 7);           // L6
    add(aw2, 100, 1, 4, 1);             // L7
    add(m3w0, 56, 150, 2, 10);          // L8
    add(m3w1, 150, 100, 5, 7);          // L9
    add(m3w2, 100, 100, 4, 7);          // L10

    k_prep<<<off, 64, 0, stream>>>(pa);

    k_main<<<NELEM/8, 256, 0, stream>>>(state, wfrag,
        m1b0, m1b1, m2b0, m2b1, ab0, ab1, ab2,
        m3b0, m3b1, m3b2, m3w3, m3b3, (float*)d_out);
}